// Round 6
// baseline (139.092 us; speedup 1.0000x reference)
//
#include <hip/hip_runtime.h>

// OverlapCalculator: pairwise IoU [50000 x 2000] fp32, row max + argmax.
// Outputs (flat fp32): pred_bbox[200000] | gt_bbox[8000] | max[50000] | argmax-as-float[50000]
//
// Two-phase, bit-exact vs numpy fp32:
//  Phase 1 (hot): per (pred, 125-gt chunk) approximate chunk max, branchless,
//    divide-free. IoU = in/(s-in), s = fl(ap+ag). Running best kept as pair
//    (bi,bs): new wins iff in*bs > bi*s (cross-mult of in/(s-in) vs bi/(bs-bi),
//    denominators = unions > 0). Each compare errs only on relative ties
//    < ~2.4e-7, so A_c = fl(bi / fl(bs-bi)) obeys M_c*(1-3.1e-5) <= A_c <= M_c
//    (M_c = true chunk max of ref fl-quotients; A_c IS the ref fl-quotient of
//    the selected pair: un_ref = fl(fl(ap+ag)-in) = fl(bs-bi)).
//  Phase 2 (16-lane group per pred): amax = max_c A_c; chunks with
//    A_c >= amax*(1-1e-4) survive (3x slack over drift => every chunk holding
//    a global-max attainer survives; pruned chunks are strictly below max).
//    Lanes scan surviving chunks' gts (8 strided slots each, clamped
//    duplicates harmless under full lex compare), computing the EXACT ref
//    expression per pair incl. IEEE divide, fp contract off. Lex (q, min idx)
//    combine per slot + 4-step butterfly => bit-exact max and numpy
//    first-occurrence argmax.

#define N_PRED 50000
#define N_GT   2000
#define CHUNKS 16
#define CHUNK  125
#define BLOCK  256
#define PPT    2
#define TMARG  0.9999f    // 1 - 1e-4 chunk prune margin (drift bound 3.1e-5)

// --- phase 1: grid (98, 16); 2 preds/thread; gt chunk in LDS ----------------
__global__ __launch_bounds__(BLOCK) void chunk_max(
        const float4* __restrict__ pred, const float4* __restrict__ gt,
        float* __restrict__ ws_amax, float* __restrict__ out) {
#pragma clang fp contract(off)
    __shared__ float4 sg[CHUNK];
    const int tid  = threadIdx.x;
    const int c    = blockIdx.y;
    const int base = c * CHUNK;
    if (tid < CHUNK) sg[tid] = gt[base + tid];
    __syncthreads();

    const int idx0 = blockIdx.x * (BLOCK * PPT) + tid;
    const int idx1 = idx0 + BLOCK;
    const float4 p0 = pred[idx0 < N_PRED ? idx0 : N_PRED - 1];
    const float4 p1 = pred[idx1 < N_PRED ? idx1 : N_PRED - 1];
    const float ap0 = (p0.z - p0.x) * (p0.w - p0.y);
    const float ap1 = (p1.z - p1.x) * (p1.w - p1.y);

    // best pair (intersection, sum-of-areas); rational value bi/(bs-bi)
    float bi0 = 0.0f, bs0 = 1.0f;
    float bi1 = 0.0f, bs1 = 1.0f;

#pragma unroll 10
    for (int j = 0; j < CHUNK; ++j) {
        const float4 g  = sg[j];                      // uniform -> broadcast
        const float  ag = (g.z - g.x) * (g.w - g.y);  // 3 VALU, shared by 2 preds

        float s0 = ap0 + ag;
        float w0 = fmaxf(fminf(p0.z, g.z) - fmaxf(p0.x, g.x), 0.0f);
        float h0 = fmaxf(fminf(p0.w, g.w) - fmaxf(p0.y, g.y), 0.0f);
        float i0 = w0 * h0;
        bool  m0 = i0 * bs0 > bi0 * s0;   // cross-mult rational compare
        bi0 = m0 ? i0 : bi0;
        bs0 = m0 ? s0 : bs0;

        float s1 = ap1 + ag;
        float w1 = fmaxf(fminf(p1.z, g.z) - fmaxf(p1.x, g.x), 0.0f);
        float h1 = fmaxf(fminf(p1.w, g.w) - fmaxf(p1.y, g.y), 0.0f);
        float i1 = w1 * h1;
        bool  m1 = i1 * bs1 > bi1 * s1;
        bi1 = m1 ? i1 : bi1;
        bs1 = m1 ? s1 : bs1;
    }
    // A_c = exact ref fl-quotient of selected pair: un = fl(bs-bi), q = fl(bi/un)
    if (idx0 < N_PRED) ws_amax[idx0 * CHUNKS + c] = bi0 / (bs0 - bi0);
    if (idx1 < N_PRED) ws_amax[idx1 * CHUNKS + c] = bi1 / (bs1 - bi1);

    // fused passthrough (y==0 blocks reuse already-loaded preds)
    if (c == 0) {
        float4* out_pred = (float4*)out;
        if (idx0 < N_PRED) out_pred[idx0] = p0;
        if (idx1 < N_PRED) out_pred[idx1] = p1;
        if (blockIdx.x == 0) {
            float4* out_gt = (float4*)(out + 4 * N_PRED);
            for (int j = tid; j < N_GT; j += BLOCK) out_gt[j] = gt[j];
        }
    }
}

// --- phase 2: 16-lane group per pred; grid 3125 x 256; branchless inner -----
__global__ __launch_bounds__(BLOCK) void resolve(
        const float* __restrict__ ws_amax,
        const float4* __restrict__ pred, const float4* __restrict__ gt,
        float* __restrict__ out) {
#pragma clang fp contract(off)
    const int gslot = blockIdx.x * BLOCK + threadIdx.x;   // 800000 slots
    const int i     = gslot >> 4;                         // pred id
    const int k     = threadIdx.x & 15;                   // lane in group
    const int lane  = threadIdx.x & 63;
    float* out_max = out + 4 * N_PRED + 4 * N_GT;
    float* out_idx = out_max + N_PRED;

    // chunk maxima: lane k holds A_k; 4-step butterfly within the 16-lane group
    float av = ws_amax[i * CHUNKS + k];                   // coalesced 256B/wave
    float amax = av;
#pragma unroll
    for (int s = 1; s < 16; s <<= 1)
        amax = fmaxf(amax, __shfl_xor(amax, s, 16));
    const float t = amax * TMARG;
    unsigned long long bal = __ballot(av >= t);
    unsigned m = (unsigned)((bal >> (lane & ~15)) & 0xFFFFull);  // group mask

    const float4 p  = pred[i];
    const float  ap = (p.z - p.x) * (p.w - p.y);

    float best = -1.0f;
    int   bidx = 0;
    while (m) {                      // ~1 chunk typical; diverges mildly across groups
        const int c = __builtin_ctz(m);
        m &= m - 1;
        const int cb = c * CHUNK;
#pragma unroll
        for (int r = 0; r < 8; ++r) {               // 8*16 = 128 slots >= 125
            const int jj = r * 16 + k;
            const int j  = cb + (jj < CHUNK ? jj : CHUNK - 1);  // dup ok (lex)
            const float4 g  = gt[j];                            // L1/L2-hot
            const float  ag = (g.z - g.x) * (g.w - g.y);        // ref fl expr
            float w  = fmaxf(fminf(p.z, g.z) - fmaxf(p.x, g.x), 0.0f);
            float h  = fmaxf(fminf(p.w, g.w) - fmaxf(p.y, g.y), 0.0f);
            float in = w * h;
            float un = (ap + ag) - in;              // ref assoc order
            float q  = in / un;                     // exact IEEE divide, always
            if (q > best || (q == best && j < bidx)) { best = q; bidx = j; }
        }
    }
    // 4-step lex (q, min idx) butterfly within the group
#pragma unroll
    for (int s = 1; s < 16; s <<= 1) {
        float oq = __shfl_xor(best, s, 16);
        int   oi = __shfl_xor(bidx, s, 16);
        if (oq > best || (oq == best && oi < bidx)) { best = oq; bidx = oi; }
    }
    if (k == 0) { out_max[i] = best; out_idx[i] = (float)bidx; }
}

extern "C" void kernel_launch(void* const* d_in, const int* in_sizes, int n_in,
                              void* d_out, int out_size, void* d_ws, size_t ws_size,
                              hipStream_t stream) {
    const float4* pred = (const float4*)d_in[0];
    const float4* gt   = (const float4*)d_in[1];
    float* out = (float*)d_out;

    float* ws_amax = (float*)d_ws;  // 50000*16 floats = 3.2 MB, pred-major

    const int gx1 = (N_PRED + BLOCK * PPT - 1) / (BLOCK * PPT);  // 98
    chunk_max<<<dim3(gx1, CHUNKS), BLOCK, 0, stream>>>(pred, gt, ws_amax, out);

    const int gx2 = (N_PRED * 16) / BLOCK;                       // 3125
    resolve<<<dim3(gx2), BLOCK, 0, stream>>>(ws_amax, pred, gt, out);
}